// Round 3
// baseline (61.627 us; speedup 1.0000x reference)
//
#include <hip/hip_runtime.h>

// Decoder: piecewise-linear curve eval.
// segment_x, segment_y: [B=8, N+1=33] fp32. Output: [B, S=196608] fp32.
//
// Semantics (proven equivalent to the reference masked-sum in round 0):
//  1) fixed knots = inclusive running-max scan of x (ties keep later entry),
//     y carried from the winning position.
//  2) per pixel xin=(s+1)/S, j = largest j in [0,31] with xs[j] <= xin
//     (== count of xs[k] <= xin over k=1..31; covers both clamps).
//  3) out = ratio[j]*(xin - xs[j]) + ys[j], ratio = dy / (dx==0 ? 1e-4 : dx).
//
// Round-3 structure: per-block segment bracket [jlo,jhi] via ballot over the
// knot lanes (avg block contains 0.33 knots -> inner loop ~0 trips), and
// bit-exact xin via one f64 multiply (correctly-rounded vs fp32 division:
// double rel-err 2^-52 << 2^-26 gap of n/(3*2^16) to fp32 boundaries).

constexpr int S = 196608;   // 3*256*256
constexpr int NK = 33;      // knots
constexpr int NSEG = 32;
constexpr int BLOCK = 256;
constexpr int EPT = 8;             // elems per thread
constexpr int EPB = BLOCK * EPT;   // 2048 elems per block
constexpr int HALF = BLOCK * 4;    // 1024: two contiguous float4 tiles

__device__ __forceinline__ float exact_xin(int sp1) {
    return (float)((double)sp1 * (1.0 / (double)S));
}

__global__ __launch_bounds__(BLOCK) void decoder_kernel(
    const float* __restrict__ seg_x,
    const float* __restrict__ seg_y,
    float* __restrict__ out)
{
    __shared__ float xs[NK];
    __shared__ float ys[NK];
    __shared__ float ratio[NSEG];
    __shared__ int jb[2];

    const int b = blockIdx.y;
    const int tid = threadIdx.x;
    const int s0 = blockIdx.x * EPB;

    // ---- knot prep: wave 0 only ----
    if (tid < 64) {
        float x = 0.0f, y = 0.0f;
        if (tid < NK) {
            x = seg_x[b * NK + tid];
            y = seg_y[b * NK + tid];
        }
        // inclusive running-max scan (later entry wins ties)
#pragma unroll
        for (int d = 1; d < 64; d <<= 1) {
            float ox = __shfl_up(x, d);
            float oy = __shfl_up(y, d);
            if (tid >= d && x < ox) { x = ox; y = oy; }
        }
        float xn = __shfl_down(x, 1);
        float yn = __shfl_down(y, 1);
        if (tid < NK) { xs[tid] = x; ys[tid] = y; }
        if (tid < NSEG) {
            float dx = xn - x;
            if (dx == 0.0f) dx = 0.0001f;
            ratio[tid] = (yn - y) / dx;
        }
        // block-uniform bracket: j(xin) = popcount over knot lanes 1..31 of
        // (xs[k] <= xin). Lanes 0,32..63 masked out.
        const float xf = exact_xin(s0 + 1);     // first xin in block
        const float xl = exact_xin(s0 + EPB);   // last xin in block
        unsigned long long mlo = __ballot(x <= xf) & 0xFFFFFFFEULL;
        unsigned long long mhi = __ballot(x <= xl) & 0xFFFFFFFEULL;
        if (tid == 0) { jb[0] = __popcll(mlo); jb[1] = __popcll(mhi); }
    }
    __syncthreads();

    const int jlo = jb[0];
    const int jhi = jb[1];
    const size_t obase = (size_t)b * S;

#pragma unroll
    for (int h = 0; h < 2; ++h) {
        const int sb = s0 + h * HALF + tid * 4;
        float r0, r1, r2, r3;
#pragma unroll
        for (int e = 0; e < 4; ++e) {
            const float xin = exact_xin(sb + e + 1);
            int j = jlo;
            // usually 0 trips; uniform bounds -> no divergence
            for (int k = jlo + 1; k <= jhi; ++k)
                j += (xin >= xs[k]) ? 1 : 0;
            const float r = fmaf(ratio[j], xin - xs[j], ys[j]);
            if (e == 0) r0 = r;
            else if (e == 1) r1 = r;
            else if (e == 2) r2 = r;
            else r3 = r;
        }
        float4 v; v.x = r0; v.y = r1; v.z = r2; v.w = r3;
        *reinterpret_cast<float4*>(&out[obase + sb]) = v;  // coalesced 16B
    }
}

extern "C" void kernel_launch(void* const* d_in, const int* in_sizes, int n_in,
                              void* d_out, int out_size, void* d_ws, size_t ws_size,
                              hipStream_t stream) {
    const float* seg_x = (const float*)d_in[0];
    const float* seg_y = (const float*)d_in[1];
    float* out = (float*)d_out;

    dim3 grid(S / EPB, 8);  // (96, 8)
    decoder_kernel<<<grid, BLOCK, 0, stream>>>(seg_x, seg_y, out);
}